// Round 5
// baseline (957.399 us; speedup 1.0000x reference)
//
#include <hip/hip_runtime.h>

using fp16 = _Float16;
typedef fp16 f16x4 __attribute__((ext_vector_type(4)));
typedef fp16 f16x8 __attribute__((ext_vector_type(8)));
typedef float f32x4 __attribute__((ext_vector_type(4)));

#define DEVI __device__ __forceinline__

constexpr int LL = 50;
constexpr int BB = 4096;
constexpr int ALPHA = 128;
constexpr int CTX = 20;
constexpr int ATT = 100;

// ---- fragment image element offsets (fp16 elems) ----
// frag linear layout: ((frag)*64 + lane)*8 + j ; frag = nt*KT + kt
constexpr int FQ_OFF  = 0;       // Wq_eff  [K=160][N=112]  NT=7 KT=5  (probs|ctx|pad)
constexpr int FF_OFF  = 17920;   // Wff_eff [K=224][N=128]  NT=8 KT=7  (probs|attn|ctx|pad)
constexpr int FR_OFF  = 46592;   // Wre     [K=128][N=32]   NT=2 KT=4
constexpr int FB_OFF  = 50688;   // Wbc     [K=32][N=32]    NT=2 KT=1
constexpr int FTQ_OFF = 51712;   // Wq tag rows [64][112]   NT=7 KT=2
constexpr int FTF_OFF = 58880;   // Wff tag rows[64][128]   NT=8 KT=2
constexpr int FRAG_TOT= 67072;

// ---- workspace byte offsets ----
constexpr size_t WS_FRAG = 0;                          // 134144 B
constexpr size_t WS_PQ   = 134144;                     // f32 [50][112] pos@Wq + bq
constexpr size_t WS_PK   = 156544;                     // f32 [50][112] pos@Wk + bk
constexpr size_t WS_TBL  = 178944;                     // f16 packed: ce[128*20] | em[128*40] | wk[112*72]
constexpr int    TBL_CE  = 0;
constexpr int    TBL_EM  = 2560;
constexpr int    TBL_WK  = 7680;
constexpr int    TBL_N   = 15744;                      // f16 elems (31488 B)
constexpr size_t WS_K    = 210432;                     // f16 [4096][50][104]
constexpr size_t WS_V    = WS_K + (size_t)BB*5200*2;   // f16 [4096][60][52]

// decoder LDS strides (f16 elems)
constexpr int XQS = 168;
constexpr int XFS = 232;
constexpr int QBS = 120;
constexpr int SCS = 136;   // f16 now

DEVI float rcpf(float x) { return __builtin_amdgcn_rcpf(x); }
DEVI float sigm(float x) { return rcpf(1.0f + __expf(-x)); }

DEVI f32x4 mfma16(f16x8 a, f16x8 b, f32x4 c) {
  return __builtin_amdgcn_mfma_f32_16x16x32_f16(a, b, c, 0, 0, 0);
}

DEVI float dot8f(f16x8 a, f16x8 b, float acc) {
  acc = __builtin_amdgcn_fdot2(__builtin_shufflevector(a,a,0,1), __builtin_shufflevector(b,b,0,1), acc, false);
  acc = __builtin_amdgcn_fdot2(__builtin_shufflevector(a,a,2,3), __builtin_shufflevector(b,b,2,3), acc, false);
  acc = __builtin_amdgcn_fdot2(__builtin_shufflevector(a,a,4,5), __builtin_shufflevector(b,b,4,5), acc, false);
  acc = __builtin_amdgcn_fdot2(__builtin_shufflevector(a,a,6,7), __builtin_shufflevector(b,b,6,7), acc, false);
  return acc;
}
DEVI float dot4f(f16x4 a, f16x4 b, float acc) {
  acc = __builtin_amdgcn_fdot2(__builtin_shufflevector(a,a,0,1), __builtin_shufflevector(b,b,0,1), acc, false);
  acc = __builtin_amdgcn_fdot2(__builtin_shufflevector(a,a,2,3), __builtin_shufflevector(b,b,2,3), acc, false);
  return acc;
}

// DPP all-VALU wave64 reductions. REQUIRES v >= 0 in all lanes (0-fill safe).
#define DPP_STEP(OP, CTRL)                                                        \
  { int t_ = __builtin_amdgcn_update_dpp(0, __builtin_bit_cast(int, v), CTRL, 0xF, 0xF, true); \
    v = OP(v, __builtin_bit_cast(float, t_)); }

DEVI float addf(float a, float b) { return a + b; }

DEVI float redmax64(float v) {
  DPP_STEP(fmaxf, 0x111) DPP_STEP(fmaxf, 0x112) DPP_STEP(fmaxf, 0x114)
  DPP_STEP(fmaxf, 0x118) DPP_STEP(fmaxf, 0x142) DPP_STEP(fmaxf, 0x143)
  return __builtin_bit_cast(float, __builtin_amdgcn_readlane(__builtin_bit_cast(int, v), 63));
}
DEVI float redsum64(float v) {
  DPP_STEP(addf, 0x111) DPP_STEP(addf, 0x112) DPP_STEP(addf, 0x114)
  DPP_STEP(addf, 0x118) DPP_STEP(addf, 0x142) DPP_STEP(addf, 0x143)
  return __builtin_bit_cast(float, __builtin_amdgcn_readlane(__builtin_bit_cast(int, v), 63));
}

// ================= setup: tables + fragment-packed weights =================
__global__ void dt_setup(const float* __restrict__ embT, const float* __restrict__ Wce,
                         const float* __restrict__ bce,
                         const float* __restrict__ Wq, const float* __restrict__ bq,
                         const float* __restrict__ Wk, const float* __restrict__ bk,
                         const float* __restrict__ Wff, const float* __restrict__ Wre,
                         const float* __restrict__ Wbc, char* __restrict__ ws) {
  __shared__ float ap[LL*60];
  const int tid = threadIdx.x, bid = blockIdx.x;
  if (bid <= 1) {
    for (int i = tid; i < LL*30; i += 256) {
      int p = i / 30, k = i % 30;
      float freq = powf(10000.f, 2.0f*(float)k/60.0f);
      float ang = (float)p / freq;
      ap[p*60 + k]      = sinf(ang);
      ap[p*60 + 30 + k] = cosf(ang);
    }
    __syncthreads();
    const float* W = (bid == 0) ? Wq : Wk;
    const float* bi = (bid == 0) ? bq : bk;
    float* dst = (float*)(ws + (bid == 0 ? WS_PQ : WS_PK));
    for (int i = tid; i < LL*112; i += 256) {
      int r = i / 112, j = i % 112;
      float a = 0.f;
      if (j < ATT) {
        a = bi[j];
        for (int f = 0; f < 60; ++f) a += ap[r*60 + f]*W[f*ATT + j];
      }
      dst[i] = a;
    }
  } else if (bid == 2) {
    fp16* tbl = (fp16*)(ws + WS_TBL);
    for (int i = tid; i < ALPHA*CTX; i += 256) {
      int r = i / CTX, o = i % CTX;
      float a = bce[o];
      for (int e = 0; e < 40; ++e) a += embT[r*40 + e]*Wce[e*CTX + o];
      tbl[TBL_CE + i] = (fp16)a;
    }
    for (int i = tid; i < ALPHA*40; i += 256) tbl[TBL_EM + i] = (fp16)embT[i];
  } else if (bid == 3) {
    fp16* tbl = (fp16*)(ws + WS_TBL);
    for (int i = tid; i < 112*72; i += 256) {
      int a = i / 72, c = i % 72;
      float v = 0.f;
      if (a < ATT) {
        if (c < 20)      v = Wk[(60 + c)*ATT + a];
        else if (c < 60) v = Wk[(80 + (c-20))*ATT + a];
      }
      tbl[TBL_WK + i] = (fp16)v;
    }
  } else {
    fp16* pw = (fp16*)(ws + WS_FRAG);
    for (int gi = (bid-4)*256 + tid; gi < FRAG_TOT; gi += 28*256) {
      int t = gi, img, base, KT;
      if      (t < FF_OFF)  { img = 0; base = t - FQ_OFF;  KT = 5; }
      else if (t < FR_OFF)  { img = 1; base = t - FF_OFF;  KT = 7; }
      else if (t < FB_OFF)  { img = 2; base = t - FR_OFF;  KT = 4; }
      else if (t < FTQ_OFF) { img = 3; base = t - FB_OFF;  KT = 1; }
      else if (t < FTF_OFF) { img = 4; base = t - FTQ_OFF; KT = 2; }
      else                  { img = 5; base = t - FTF_OFF; KT = 2; }
      int j = base & 7, lane = (base >> 3) & 63, frag = base >> 9;
      int nt = frag / KT, kt = frag % KT;
      int k = kt*32 + ((lane >> 4) << 3) + j;
      int n = nt*16 + (lane & 15);
      float v = 0.f;
      if (img == 0) {
        if (n < ATT) {
          if (k < 128)      v = Wq[(80 + k)*ATT + n];
          else if (k < 148) v = Wq[(60 + (k - 128))*ATT + n];
        }
      } else if (img == 1) {
        if (k < 128)      v = Wff[(228 + k)*ALPHA + n];
        else if (k < 188) v = Wff[(k - 128)*ALPHA + n];
        else if (k < 208) v = Wff[(208 + (k - 188))*ALPHA + n];
      } else if (img == 2) {
        if (k < 128 && n < CTX) v = Wre[k*CTX + n];
      } else if (img == 3) {
        if (k < CTX && n < CTX) v = Wbc[k*CTX + n];
      } else if (img == 4) {
        if (n < ATT && k < 64)  v = Wq[(208 + k)*ATT + n];
      } else {
        if (k < 64)             v = Wff[(356 + k)*ALPHA + n];
      }
      pw[gi] = (fp16)v;
    }
  }
}

// ================= encode: ctxt + K + V, one batch elem per block =================
__global__ void dt_encode(const int* __restrict__ lemma,
    const float* __restrict__ Wb4, const float* __restrict__ bb4,
    const float* __restrict__ Waft, const float* __restrict__ baft,
    const float* __restrict__ Wall, const float* __restrict__ ball,
    char* __restrict__ ws) {
  __shared__ fp16 wkl[112*72];          // 16.1 KB
  __shared__ float wb4[800], wa[400], wl[800];
  __shared__ float cel[LL*CTX], b4l[LL*CTX], afl[LL*CTX];
  __shared__ fp16 xin[LL*72];
  __shared__ float bi4[CTX], biA[CTX], biL[CTX];
  __shared__ int lem[52];
  const int b = blockIdx.x, tid = threadIdx.x;
  const fp16* ceg = (const fp16*)(ws + WS_TBL) + TBL_CE;   // 5 KB, L1-hot
  const fp16* emg = (const fp16*)(ws + WS_TBL) + TBL_EM;   // 10 KB, L1-hot

  { const uint4* s = (const uint4*)((const fp16*)(ws + WS_TBL) + TBL_WK);
    uint4* d = (uint4*)wkl;
    for (int i = tid; i < 112*72*2/16; i += 256) d[i] = s[i]; }
  { const float4* s = (const float4*)Wb4; float4* d = (float4*)wb4;
    for (int i = tid; i < 200; i += 256) d[i] = s[i]; }
  { const float4* s = (const float4*)Waft; float4* d = (float4*)wa;
    for (int i = tid; i < 100; i += 256) d[i] = s[i]; }
  { const float4* s = (const float4*)Wall; float4* d = (float4*)wl;
    for (int i = tid; i < 200; i += 256) d[i] = s[i]; }
  if (tid < CTX) { bi4[tid] = bb4[tid]; biA[tid] = baft[tid]; biL[tid] = ball[tid]; }
  if (tid < LL) lem[tid] = lemma[tid*BB + b];
  __syncthreads();

  for (int i = tid; i < LL*CTX; i += 256)
    cel[i] = (float)ceg[lem[i/CTX]*CTX + (i % CTX)];
  __syncthreads();

  for (int i = tid; i < LL*CTX; i += 256) {
    int l = i / CTX, o = i % CTX;
    float a = bi4[o];
    for (int c = 0; c < CTX; ++c) {
      float c2 = (l >= 2) ? cel[(l-2)*CTX + c] : 0.f;
      float c1 = (l >= 1) ? cel[(l-1)*CTX + c] : 0.f;
      a += c2*wb4[c*CTX + o] + c1*wb4[(CTX+c)*CTX + o];
    }
    b4l[i] = sigm(a);
    float af = biA[o];
    if (l < LL-1)
      for (int c = 0; c < CTX; ++c) af += cel[(l+1)*CTX + c]*wa[c*CTX + o];
    afl[i] = sigm(af);
  }
  __syncthreads();

  for (int i = tid; i < LL*CTX; i += 256) {
    int l = i / CTX, o = i % CTX;
    float a = biL[o];
    for (int c = 0; c < CTX; ++c)
      a += b4l[l*CTX + c]*wl[c*CTX + o] + afl[l*CTX + c]*wl[(CTX+c)*CTX + o];
    xin[l*72 + o] = (fp16)sigm(a);
  }
  for (int i = tid; i < LL*40; i += 256) {
    int l = i / 40, d = i % 40;
    xin[l*72 + 20 + d] = emg[lem[l]*40 + d];
  }
  for (int i = tid; i < LL*12; i += 256) {
    int l = i / 12, c = i % 12;
    xin[l*72 + 60 + c] = (fp16)0.f;
  }
  __syncthreads();

  const float* pkg = (const float*)(ws + WS_PK);
  fp16* Kw = (fp16*)(ws + WS_K) + (size_t)b*5200;
  for (int i = tid; i < 5200; i += 256) {
    int l = i / 104, a = i % 104;
    fp16 v = (fp16)0.f;
    if (a < ATT) {
      float acc = pkg[l*112 + a];
      const fp16* x = xin + l*72;
      const fp16* wv = wkl + a*72;
      #pragma unroll
      for (int k = 0; k < 9; ++k)
        acc = dot8f(*(const f16x8*)(x + 8*k), *(const f16x8*)(wv + 8*k), acc);
      v = (fp16)sigm(acc);
    }
    Kw[i] = v;
  }
  fp16* Vw = (fp16*)(ws + WS_V) + (size_t)b*3120;
  for (int i = tid; i < 3120; i += 256) {
    int d = i / 52, l = i % 52;
    Vw[i] = (l < LL) ? xin[l*72 + d] : (fp16)0.f;
  }
}

// ========== decoder: MFMA weights in VGPRs, DPP softmax, ~33 KB LDS, 2 blocks/CU ==========
__global__ __launch_bounds__(512, 4)
void dt_decoder(const char* __restrict__ ws, const float* __restrict__ tags,
                const float* __restrict__ Wre, const float* __restrict__ b_re,
                const float* __restrict__ b_bc, const float* __restrict__ bff,
                float* __restrict__ out) {
  __shared__ fp16 xq[16*XQS];
  __shared__ fp16 xf[16*XFS];
  __shared__ fp16 rp[16*40];
  __shared__ fp16 qb[16*QBS];
  __shared__ fp16 sc[16*SCS];
  __shared__ fp16 atb[8*56];
  __shared__ float tagq[8*112];
  __shared__ float tagf[8*128];
  __shared__ fp16 tagsl[16*72];
  __shared__ float brel[32], bbcl[32];

  const int tid = threadIdx.x, lane = tid & 63, w = tid >> 6;
  const int b0 = blockIdx.x * 8;
  const int b = b0 + w;
  const float* posqg = (const float*)(ws + WS_PQ);   // L1-hot 22.4 KB table

  // ---- zero-init LDS state ----
  for (int i = tid; i < 16*XQS; i += 512) xq[i] = (fp16)0.f;
  for (int i = tid; i < 16*XFS; i += 512) xf[i] = (fp16)0.f;
  for (int i = tid; i < 16*40; i += 512) rp[i] = (fp16)0.f;
  for (int i = tid; i < 8*56; i += 512) atb[i] = (fp16)0.f;
  for (int i = tid; i < 16*72; i += 512) tagsl[i] = (fp16)0.f;
  if (tid < 32) { brel[tid] = (tid < CTX) ? b_re[tid] : 0.f;
                  bbcl[tid] = (tid < CTX) ? b_bc[tid] : 0.f; }
  for (int i = tid; i < 8*64; i += 512) {
    int e = i >> 6, c = i & 63;
    tagsl[e*72 + c] = (fp16)tags[(size_t)(b0 + e)*64 + c];
  }
  if (tid < 8) { xq[tid*XQS + 1] = (fp16)1.f; xf[tid*XFS + 1] = (fp16)1.f; }
  // ctx(1) = sigm(b_bc) ; r[0] = sigm(Wre[1,:] + b_re)
  if (tid < 160) {
    int e = tid / CTX, o = tid % CTX;
    float c1 = sigm(b_bc[o]);
    xq[e*XQS + 128 + o] = (fp16)c1;
    xf[e*XFS + 188 + o] = (fp16)c1;
    rp[e*40 + o] = (fp16)sigm(Wre[CTX + o] + b_re[o]);
  }
  for (int i = tid; i < 1024; i += 512) {
    int e = i >> 7, o = i & 127;
    out[(size_t)(b0 + e)*ALPHA + o] = (o == 1) ? 1.f : 0.f;
  }

  // ---- weight fragments into VGPRs ----
  const fp16* fw = (const fp16*)(ws + WS_FRAG);
  f16x8 wA[8], wB[7], wC[2], wD[2];
  if (w < 7) {
    #pragma unroll
    for (int kt = 0; kt < 5; ++kt)
      wA[kt] = *(const f16x8*)(fw + FQ_OFF + (((w*5 + kt) << 6) + lane)*8);
    #pragma unroll
    for (int kt = 0; kt < 2; ++kt)
      wC[kt] = *(const f16x8*)(fw + FTQ_OFF + (((w*2 + kt) << 6) + lane)*8);
  } else {
    #pragma unroll
    for (int t = 0; t < 8; ++t)
      wA[t] = *(const f16x8*)(fw + FR_OFF + ((t << 6) + lane)*8);
    #pragma unroll
    for (int t = 0; t < 2; ++t)
      wC[t] = *(const f16x8*)(fw + FB_OFF + ((t << 6) + lane)*8);
  }
  #pragma unroll
  for (int kt = 0; kt < 7; ++kt)
    wB[kt] = *(const f16x8*)(fw + FF_OFF + (((w*7 + kt) << 6) + lane)*8);
  #pragma unroll
  for (int kt = 0; kt < 2; ++kt)
    wD[kt] = *(const f16x8*)(fw + FTF_OFF + (((w*2 + kt) << 6) + lane)*8);

  // ---- K/V into registers ----
  f16x8 Kr[12]; f16x4 Kr12; f16x4 Vr[13];
  { const fp16* kg = (const fp16*)(ws + WS_K) + (size_t)b*5200 + (lane < LL ? lane : LL-1)*104;
    #pragma unroll
    for (int k = 0; k < 12; ++k) Kr[k] = *(const f16x8*)(kg + 8*k);
    Kr12 = *(const f16x4*)(kg + 96); }
  { const fp16* vg = (const fp16*)(ws + WS_V) + (size_t)b*3120 + (lane < 60 ? lane : 59)*52;
    #pragma unroll
    for (int k = 0; k < 13; ++k) Vr[k] = *(const f16x4*)(vg + 4*k); }

  const float bffr = bff[w*16 + (lane & 15)];
  __syncthreads();

  // ---- tag projections via MFMA ----
  {
    const int arow = lane & 15, koff = (lane >> 4)*8;
    f16x8 a0 = *(const f16x8*)(tagsl + arow*72 + koff);
    f16x8 a1 = *(const f16x8*)(tagsl + arow*72 + 32 + koff);
    const int r0 = (lane >> 4)*4, colg = w*16 + (lane & 15);
    if (w < 7) {
      f32x4 c = {0.f,0.f,0.f,0.f};
      c = mfma16(a0, wC[0], c); c = mfma16(a1, wC[1], c);
      #pragma unroll
      for (int r = 0; r < 4; ++r) { int rr = r0 + r; if (rr < 8) tagq[rr*112 + colg] = c[r]; }
    }
    f32x4 d = {0.f,0.f,0.f,0.f};
    d = mfma16(a0, wD[0], d); d = mfma16(a1, wD[1], d);
    #pragma unroll
    for (int r = 0; r < 4; ++r) { int rr = r0 + r; if (rr < 8) tagf[rr*128 + colg] = d[r] + bffr; }
  }
  __syncthreads();

  float pA = 0.f, pB = 0.f;   // probs of previous step, stored at top of phase A

  // ==================== recurrence ====================
  for (int i = 1; i < LL; ++i) {
    // ---- Phase A: deferred out-store + q-GEMM (w0-6) + r/ctx-GEMM (w7) ----
    if (i > 1) {
      size_t ob = ((size_t)(i-1)*BB + b)*ALPHA;
      out[ob + lane] = pA; out[ob + 64 + lane] = pB;
    }
    {
      const int arow = lane & 15, koff = (lane >> 4)*8;
      const int r0 = (lane >> 4)*4;
      if (w < 7) {
        const int colg = w*16 + (lane & 15);
        float pos = posqg[i*112 + colg];          // issue early, L1-hot
        f32x4 c = {0.f,0.f,0.f,0.f};
        #pragma unroll
        for (int kt = 0; kt < 5; ++kt)
          c = mfma16(*(const f16x8*)(xq + arow*XQS + kt*32 + koff), wA[kt], c);
        #pragma unroll
        for (int r = 0; r < 4; ++r) {
          int rr = r0 + r;
          if (rr < 8)
            qb[rr*QBS + colg] = (fp16)sigm(c[r] + pos + tagq[rr*112 + colg]);
        }
      } else {
        // r[i-1] = sig(probs[i-1] @ Wre + bre)
        f32x4 c0 = {0.f,0.f,0.f,0.f}, c1 = {0.f,0.f,0.f,0.f};
        #pragma unroll
        for (int kt = 0; kt < 4; ++kt) {
          f16x8 a = *(const f16x8*)(xq + arow*XQS + kt*32 + koff);
          c0 = mfma16(a, wA[kt],     c0);
          c1 = mfma16(a, wA[4 + kt], c1);
        }
        const int cA = lane & 15, cB = 16 + (lane & 15);
        #pragma unroll
        for (int r = 0; r < 4; ++r) {
          int rr = r0 + r;
          if (rr < 8) {
            if (cA < CTX) rp[rr*40 + cA] = (fp16)sigm(c0[r] + brel[cA]);
            if (cB < CTX) rp[rr*40 + cB] = (fp16)sigm(c1[r] + brel[cB]);
          }
        }
        // ctx(i+1) = sig(r[i-1] @ Wbc + bbc)   (same-wave LDS ordering via lgkmcnt)
        f16x8 ar = *(const f16x8*)(rp + arow*40 + koff);
        f32x4 d0 = {0.f,0.f,0.f,0.f}, d1 = {0.f,0.f,0.f,0.f};
        d0 = mfma16(ar, wC[0], d0);
        d1 = mfma16(ar, wC[1], d1);
        #pragma unroll
        for (int r = 0; r < 4; ++r) {
          int rr = r0 + r;
          if (rr < 8) {
            if (cA < CTX) {
              float cv = sigm(d0[r] + bbcl[cA]);
              xq[rr*XQS + 128 + cA] = (fp16)cv;
              xf[rr*XFS + 188 + cA] = (fp16)cv;
            }
            if (cB < CTX) {
              float cv = sigm(d1[r] + bbcl[cB]);
              xq[rr*XQS + 128 + cB] = (fp16)cv;
              xf[rr*XFS + 188 + cB] = (fp16)cv;
            }
          }
        }
      }
    }
    __syncthreads();

    // ---- Phase B (wave e=w): scores, DPP softmax-50, in_attn ----
    {
      const fp16* qrow = qb + w*QBS;
      float a0 = 0.f, a1 = 0.f;
      #pragma unroll
      for (int k = 0; k < 12; k += 2) {
        a0 = dot8f(*(const f16x8*)(qrow + 8*k),     Kr[k],   a0);
        a1 = dot8f(*(const f16x8*)(qrow + 8*(k+1)), Kr[k+1], a1);
      }
      a0 = dot4f(*(const f16x4*)(qrow + 96), Kr12, a0);
      float s = (lane < LL) ? (a0 + a1) : 0.f;      // scores >= 0
      float m  = redmax64(s);
      float e  = (lane < LL) ? __expf(s - m) : 0.f;
      float su = redsum64(e);
      if (lane < LL) atb[w*56 + lane] = (fp16)(e * rcpf(su));
      const fp16* ar = atb + w*56;
      float v0 = 0.f, v1 = 0.f;
      #pragma unroll
      for (int k = 0; k < 12; k += 2) {
        v0 = dot4f(*(const f16x4*)(ar + 4*k),     Vr[k],   v0);
        v1 = dot4f(*(const f16x4*)(ar + 4*(k+1)), Vr[k+1], v1);
      }
      v0 = dot4f(*(const f16x4*)(ar + 48), Vr[12], v0);
      if (lane < 60) xf[w*XFS + 128 + lane] = (fp16)(v0 + v1);
    }
    __syncthreads();

    // ---- Phase C (all waves): s = sig(xf @ Wff + tagf) ----
    {
      const int arow = lane & 15, koff = (lane >> 4)*8;
      f32x4 c = {0.f,0.f,0.f,0.f};
      #pragma unroll
      for (int kt = 0; kt < 7; ++kt)
        c = mfma16(*(const f16x8*)(xf + arow*XFS + kt*32 + koff), wB[kt], c);
      const int r0 = (lane >> 4)*4, colg = w*16 + (lane & 15);
      #pragma unroll
      for (int r = 0; r < 4; ++r) {
        int rr = r0 + r;
        if (rr < 8)
          sc[rr*SCS + colg] = (fp16)sigm(c[r] + tagf[rr*128 + colg]);
      }
    }
    __syncthreads();

    // ---- Phase D (wave e=w): DPP softmax-128, update probs (out-store deferred) ----
    {
      float v0 = (float)sc[w*SCS + lane], v1 = (float)sc[w*SCS + 64 + lane];  // sigm > 0
      float m = redmax64(fmaxf(v0, v1));
      float e0 = __expf(v0 - m), e1 = __expf(v1 - m);
      float su = redsum64(e0 + e1);
      float inv = rcpf(su);
      pA = e0 * inv; pB = e1 * inv;
      xq[w*XQS + lane] = (fp16)pA; xq[w*XQS + 64 + lane] = (fp16)pB;
      xf[w*XFS + lane] = (fp16)pA; xf[w*XFS + 64 + lane] = (fp16)pB;
    }
    __syncthreads();
  }
  { size_t ob = ((size_t)(LL-1)*BB + b)*ALPHA;
    out[ob + lane] = pA; out[ob + 64 + lane] = pB; }
}

extern "C" void kernel_launch(void* const* d_in, const int* in_sizes, int n_in,
                              void* d_out, int out_size, void* d_ws, size_t ws_size,
                              hipStream_t stream) {
  (void)in_sizes; (void)n_in; (void)out_size; (void)ws_size;
  const int*   lemma = (const int*)  d_in[0];
  const float* tags  = (const float*)d_in[1];
  const float* embT  = (const float*)d_in[2];
  const float* Wce   = (const float*)d_in[3];
  const float* bce   = (const float*)d_in[4];
  const float* Wb4   = (const float*)d_in[5];
  const float* bb4   = (const float*)d_in[6];
  const float* Waft  = (const float*)d_in[7];
  const float* baft  = (const float*)d_in[8];
  const float* Wall  = (const float*)d_in[9];
  const float* ball  = (const float*)d_in[10];
  const float* Wre   = (const float*)d_in[11];
  const float* bre   = (const float*)d_in[12];
  const float* Wbc   = (const float*)d_in[13];
  const float* bbc   = (const float*)d_in[14];
  const float* Wq    = (const float*)d_in[15];
  const float* bq    = (const float*)d_in[16];
  const float* Wk    = (const float*)d_in[17];
  const float* bk    = (const float*)d_in[18];
  const float* Wff   = (const float*)d_in[19];
  const float* bff   = (const float*)d_in[20];
  char* ws = (char*)d_ws;
  float* out = (float*)d_out;

  dt_setup<<<32, 256, 0, stream>>>(embT, Wce, bce, Wq, bq, Wk, bk, Wff, Wre, Wbc, ws);
  dt_encode<<<BB, 256, 0, stream>>>(lemma, Wb4, bb4, Waft, baft, Wall, ball, ws);
  dt_decoder<<<BB/8, 512, 0, stream>>>(ws, tags, Wre, bre, bbc, bff, out);
}